// Round 1
// baseline (565.133 us; speedup 1.0000x reference)
//
#include <hip/hip_runtime.h>

typedef __bf16 bf16_t;
typedef bf16_t bf16x8 __attribute__((ext_vector_type(8)));
typedef float f32x4 __attribute__((ext_vector_type(4)));

#define DEV static __device__ __forceinline__

constexpr float kBnScale = 0.999995000037499375f;  // 1/sqrt(1+1e-5)

DEV unsigned short f2bf(float f) {
  unsigned u = __builtin_bit_cast(unsigned, f);
  u += 0x7fffu + ((u >> 16) & 1u);
  return (unsigned short)(u >> 16);
}
DEV float bf2f(unsigned short s) {
  return __builtin_bit_cast(float, ((unsigned)s) << 16);
}
DEV f32x4 mfma16(bf16x8 a, bf16x8 b, f32x4 c) {
  return __builtin_amdgcn_mfma_f32_16x16x32_bf16(a, b, c, 0, 0, 0);
}
DEV unsigned swz(unsigned byteoff, unsigned row) { return byteoff ^ ((row & 7u) << 4); }

// ---------------------------------------------------------------- prep: xv = (x*fi)@W_in + b_in ; LayerNorm -> hv [64][128]
__global__ void k_prep_vec(const float* __restrict__ x, const float* __restrict__ fi,
                           const float* __restrict__ Win, const float* __restrict__ bin,
                           const float* __restrict__ lng, const float* __restrict__ lnb,
                           float* __restrict__ hv) {
  const int bs = blockIdx.x, t = threadIdx.x;  // 128 threads
  float acc = bin[t];
  for (int f = 0; f < 64; ++f) acc += x[bs * 64 + f] * fi[f] * Win[f * 128 + t];
  __shared__ float sred[2];
  float ssum = acc;
  for (int m = 1; m < 64; m <<= 1) ssum += __shfl_xor(ssum, m);
  if ((t & 63) == 0) sred[t >> 6] = ssum;
  __syncthreads();
  const float mu = (sred[0] + sred[1]) * (1.0f / 128.0f);
  const float d = acc - mu;
  float vsum = d * d;
  for (int m = 1; m < 64; m <<= 1) vsum += __shfl_xor(vsum, m);
  __syncthreads();
  if ((t & 63) == 0) sred[t >> 6] = vsum;
  __syncthreads();
  const float var = (sred[0] + sred[1]) * (1.0f / 128.0f);
  hv[bs * 128 + t] = d / sqrtf(var + 1e-5f) * lng[t] + lnb[t];
}

// ---------------------------------------------------------------- adjacency -> ELL (u16 cols, cap 128) + dinv
__global__ __launch_bounds__(256) void k_adj(const float* __restrict__ adj,
                                             unsigned short* __restrict__ cols,
                                             int* __restrict__ cnt, float* __restrict__ dinv) {
  const int w = threadIdx.x >> 6, lane = threadIdx.x & 63;
  const long row = (long)blockIdx.x * 4 + w;
  const float* ap = adj + row * 1024;
  unsigned short* cp = cols + row * 128;
  int c = 0;
  for (int it = 0; it < 16; ++it) {
    const float v = ap[it * 64 + lane];
    const unsigned long long m = __ballot(v != 0.0f);
    const int pos = c + __popcll(m & ((1ull << lane) - 1ull));
    if (v != 0.0f && pos < 128) cp[pos] = (unsigned short)(it * 64 + lane);
    c += __popcll(m);
  }
  if (lane == 0) {
    cnt[row] = c;
    dinv[row] = 1.0f / sqrtf((float)(c + 1));
  }
}

// ---------------------------------------------------------------- broadcast hv -> h [65536][128] fp32
__global__ void k_bcast(const float* __restrict__ hv, float* __restrict__ h) {
  const int stride = gridDim.x * blockDim.x;
  for (int i = blockIdx.x * blockDim.x + threadIdx.x; i < 65536 * 32; i += stride) {
    const int row = i >> 5, bs = row >> 10, c4 = i & 31;
    ((float4*)h)[i] = ((const float4*)hv)[bs * 32 + c4];
  }
}

// ---------------------------------------------------------------- generic MFMA GEMM: [65536,128] @ [128,NOUT]
// EPI: 0 = *dinv -> bf16 (hw')   1 = +bqkv -> bf16 qkv panel   2 = h += relu(+bo)   3 = (+b_out)*mask -> fp32 out
template <int NOUT, int EPI, bool ABF16, bool BTRANS, bool ADDHV>
__global__ __launch_bounds__(256) void k_gemm(const void* __restrict__ Ap, const float* __restrict__ W,
                                              const float* __restrict__ bias, const float* __restrict__ dinv,
                                              const float* __restrict__ hv, const float* __restrict__ mask,
                                              float* __restrict__ hF, void* __restrict__ Op) {
  __shared__ __align__(16) unsigned short Ab[128 * 128];
  __shared__ __align__(16) unsigned short Bb[NOUT * 128];
  const int t = threadIdx.x;
  const long blockRow = (long)blockIdx.x * 128;
  const int pan = blockIdx.y;
  const float* Wsrc = W + (long)pan * 128 * 128;

  if constexpr (ABF16) {
    const unsigned short* As = (const unsigned short*)Ap + blockRow * 128;
#pragma unroll
    for (int i = 0; i < 16; ++i) {
      const int f = (t + i * 256) * 4;
      const unsigned row = f >> 7, k = f & 127;
      const uint2 u = *(const uint2*)(As + f);
      *(uint2*)(Ab + (swz(row * 256u + k * 2u, row) >> 1)) = u;
    }
  } else {
    const float* As = (const float*)Ap + blockRow * 128;
    const int bs = (int)(blockRow >> 10);
#pragma unroll
    for (int i = 0; i < 16; ++i) {
      const int f = (t + i * 256) * 4;
      const unsigned row = f >> 7, k = f & 127;
      float4 v = *(const float4*)(As + f);
      if constexpr (ADDHV) {
        const float4 a = *(const float4*)(hv + bs * 128 + k);
        v.x += a.x; v.y += a.y; v.z += a.z; v.w += a.w;
      }
      uint2 u;
      u.x = f2bf(v.x) | ((unsigned)f2bf(v.y) << 16);
      u.y = f2bf(v.z) | ((unsigned)f2bf(v.w) << 16);
      *(uint2*)(Ab + (swz(row * 256u + k * 2u, row) >> 1)) = u;
    }
  }

  if constexpr (!BTRANS) {  // W stored [NOUT][128] (n-major): direct copy into Bb[n][k]
    constexpr int ITER = NOUT * 128 / 1024;
#pragma unroll
    for (int i = 0; i < ITER; ++i) {
      const int f = (t + i * 256) * 4;
      const unsigned n = f >> 7, k = f & 127;
      const float4 v = *(const float4*)(Wsrc + f);
      uint2 u;
      u.x = f2bf(v.x) | ((unsigned)f2bf(v.y) << 16);
      u.y = f2bf(v.z) | ((unsigned)f2bf(v.w) << 16);
      *(uint2*)(Bb + (swz(n * 256u + k * 2u, n) >> 1)) = u;
    }
  } else {  // W stored [128][NOUT] ([k][n]): transpose into Bb[n][k]
    const int n = t % NOUT;
    const int kg = t / NOUT;
    constexpr int KSPAN = 128 / (256 / NOUT);
#pragma unroll
    for (int kb = 0; kb < KSPAN / 8; ++kb) {
      const int k0 = kg * KSPAN + kb * 8;
      unsigned short e[8];
#pragma unroll
      for (int j = 0; j < 8; ++j) e[j] = f2bf(Wsrc[(long)(k0 + j) * NOUT + n]);
      uint4 u;
      u.x = e[0] | ((unsigned)e[1] << 16);
      u.y = e[2] | ((unsigned)e[3] << 16);
      u.z = e[4] | ((unsigned)e[5] << 16);
      u.w = e[6] | ((unsigned)e[7] << 16);
      *(uint4*)(Bb + (swz((unsigned)n * 256u + (unsigned)k0 * 2u, n) >> 1)) = u;
    }
  }
  __syncthreads();

  const int lane = t & 63;
  const int w = t >> 6, wr = w >> 1, wc = w & 1;
  constexpr int NT = NOUT / 32;
  const f32x4 vzero = {0.f, 0.f, 0.f, 0.f};
  f32x4 acc[4][NT];
#pragma unroll
  for (int a = 0; a < 4; ++a)
#pragma unroll
    for (int b = 0; b < NT; ++b) acc[a][b] = vzero;

#pragma unroll
  for (int kk = 0; kk < 4; ++kk) {
    const unsigned kb = kk * 64u + ((lane >> 4) << 4);
    bf16x8 af[4], bfr[NT];
#pragma unroll
    for (int mt = 0; mt < 4; ++mt) {
      const unsigned row = wr * 64 + mt * 16 + (lane & 15);
      af[mt] = *(const bf16x8*)(Ab + (swz(row * 256u + kb, row) >> 1));
    }
#pragma unroll
    for (int nt = 0; nt < NT; ++nt) {
      const unsigned col = wc * (NOUT / 2) + nt * 16 + (lane & 15);
      bfr[nt] = *(const bf16x8*)(Bb + (swz(col * 256u + kb, col) >> 1));
    }
#pragma unroll
    for (int mt = 0; mt < 4; ++mt)
#pragma unroll
      for (int nt = 0; nt < NT; ++nt) acc[mt][nt] = mfma16(af[mt], bfr[nt], acc[mt][nt]);
  }

#pragma unroll
  for (int mt = 0; mt < 4; ++mt) {
#pragma unroll
    for (int nt = 0; nt < NT; ++nt) {
#pragma unroll
      for (int r = 0; r < 4; ++r) {
        const long gRow = blockRow + wr * 64 + mt * 16 + ((lane >> 4) << 2) + r;
        const int gCol = wc * (NOUT / 2) + nt * 16 + (lane & 15);
        float v = acc[mt][nt][r];
        if constexpr (EPI == 0) {
          v *= dinv[gRow];
          ((unsigned short*)Op)[gRow * 128 + gCol] = f2bf(v);
        } else if constexpr (EPI == 1) {
          v += bias[pan * 128 + gCol];
          ((unsigned short*)Op)[gRow * 384 + pan * 128 + gCol] = f2bf(v);
        } else if constexpr (EPI == 2) {
          v += bias[gCol];
          v = v > 0.f ? v : 0.f;
          hF[gRow * 128 + gCol] += v;
        } else {
          v += bias[gCol];
          v *= mask[gRow >> 10];
          ((float*)Op)[gRow * 64 + gCol] = v;
        }
      }
    }
  }
}

// ---------------------------------------------------------------- SpMM: hc = BN(dinv_i*(sum_nbr hw' + hw'_self) + gcn_b) -> bf16
__global__ __launch_bounds__(256) void k_spmm(const unsigned* __restrict__ hwp,
                                              const unsigned short* __restrict__ cols,
                                              const int* __restrict__ cnt, const float* __restrict__ dinv,
                                              const float* __restrict__ gb, const float* __restrict__ bng,
                                              const float* __restrict__ bnb, unsigned* __restrict__ hc) {
  int b = blockIdx.x;
  b = (b & 7) * 2048 + (b >> 3);  // XCD-chunked swizzle: each XCD works on 8 contiguous graphs (L2-resident)
  const int w = threadIdx.x >> 6, lane = threadIdx.x & 63;
  const long row = (long)b * 4 + w;
  __shared__ unsigned short scol[4][128];
  scol[w][lane] = cols[row * 128 + lane];
  scol[w][lane + 64] = cols[row * 128 + 64 + lane];
  const int cn = cnt[row] < 128 ? cnt[row] : 128;
  const long bsbase = row & ~1023L;
  const unsigned us = hwp[row * 64 + lane];
  float a0 = bf2f((unsigned short)us), a1 = bf2f((unsigned short)(us >> 16));
  int i = 0;
  for (; i + 4 <= cn; i += 4) {
    const int j0 = scol[w][i], j1 = scol[w][i + 1], j2 = scol[w][i + 2], j3 = scol[w][i + 3];
    const unsigned u0 = hwp[(bsbase + j0) * 64 + lane];
    const unsigned u1 = hwp[(bsbase + j1) * 64 + lane];
    const unsigned u2 = hwp[(bsbase + j2) * 64 + lane];
    const unsigned u3 = hwp[(bsbase + j3) * 64 + lane];
    a0 += bf2f((unsigned short)u0) + bf2f((unsigned short)u1) + bf2f((unsigned short)u2) + bf2f((unsigned short)u3);
    a1 += bf2f((unsigned short)(u0 >> 16)) + bf2f((unsigned short)(u1 >> 16)) +
          bf2f((unsigned short)(u2 >> 16)) + bf2f((unsigned short)(u3 >> 16));
  }
  for (; i < cn; ++i) {
    const unsigned uu = hwp[(bsbase + scol[w][i]) * 64 + lane];
    a0 += bf2f((unsigned short)uu);
    a1 += bf2f((unsigned short)(uu >> 16));
  }
  const float di = dinv[row];
  const int c0 = lane * 2, c1 = c0 + 1;
  const float o0 = (di * a0 + gb[c0]) * (kBnScale * bng[c0]) + bnb[c0];
  const float o1 = (di * a1 + gb[c1]) * (kBnScale * bng[c1]) + bnb[c1];
  hc[row * 64 + lane] = (unsigned)f2bf(o0) | ((unsigned)f2bf(o1) << 16);
}

// ---------------------------------------------------------------- chunked MHA: block = one 128-node chunk, wave = one head
__global__ __launch_bounds__(256) void k_attn(const unsigned short* __restrict__ qkv,
                                              unsigned short* __restrict__ obuf) {
  __shared__ __align__(16) unsigned short vT[4 * 32 * 128];  // [head][dh][m], swizzled
  __shared__ __align__(16) unsigned short pl[4 * 32 * 128];  // [head][q][m], swizzled
  const int t = threadIdx.x, lane = t & 63, hd = t >> 6;
  const long cb = (long)blockIdx.x * 128;

  {  // stage v transposed (all threads, all heads)
    const int m = t >> 1, half = t & 1;
    const unsigned short* vrow = qkv + (cb + m) * 384 + 256 + half * 64;
#pragma unroll
    for (int c8 = 0; c8 < 8; ++c8) {
      const uint4 u = *(const uint4*)(vrow + c8 * 8);
      const int col0 = half * 64 + c8 * 8;
      unsigned short* vb = vT + (col0 >> 5) * 4096;
      const int dh0 = col0 & 31;
      const unsigned short e[8] = {(unsigned short)u.x, (unsigned short)(u.x >> 16),
                                   (unsigned short)u.y, (unsigned short)(u.y >> 16),
                                   (unsigned short)u.z, (unsigned short)(u.z >> 16),
                                   (unsigned short)u.w, (unsigned short)(u.w >> 16)};
#pragma unroll
      for (int j = 0; j < 8; ++j) {
        const unsigned dh = dh0 + j;
        vb[swz(dh * 256u + (unsigned)m * 2u, dh) >> 1] = e[j];
      }
    }
  }
  bf16x8 kf[8];
#pragma unroll
  for (int nt = 0; nt < 8; ++nt)
    kf[nt] = *(const bf16x8*)(qkv + (cb + nt * 16 + (lane & 15)) * 384 + 128 + hd * 32 + ((lane >> 4) << 3));
  __syncthreads();

  const unsigned short* vbb = vT + hd * 4096;
  unsigned short* pb = pl + hd * 4096;
  const float SC = 0.17677669529663687f * 1.4426950408889634f;  // dh^-0.5 * log2(e)
  const f32x4 vzero = {0.f, 0.f, 0.f, 0.f};

#pragma unroll 1
  for (int p = 0; p < 4; ++p) {
    bf16x8 qf[2];
#pragma unroll
    for (int mt = 0; mt < 2; ++mt)
      qf[mt] = *(const bf16x8*)(qkv + (cb + p * 32 + mt * 16 + (lane & 15)) * 384 + hd * 32 + ((lane >> 4) << 3));
    f32x4 s[2][8];
#pragma unroll
    for (int mt = 0; mt < 2; ++mt)
#pragma unroll
      for (int nt = 0; nt < 8; ++nt) s[mt][nt] = vzero;
#pragma unroll
    for (int nt = 0; nt < 8; ++nt)
#pragma unroll
      for (int mt = 0; mt < 2; ++mt) s[mt][nt] = mfma16(qf[mt], kf[nt], s[mt][nt]);

    float rinv[2][4];
#pragma unroll
    for (int mt = 0; mt < 2; ++mt) {
#pragma unroll
      for (int r = 0; r < 4; ++r) {
        float mx = s[mt][0][r];
#pragma unroll
        for (int nt = 1; nt < 8; ++nt) mx = fmaxf(mx, s[mt][nt][r]);
#pragma unroll
        for (int msk = 1; msk < 16; msk <<= 1) mx = fmaxf(mx, __shfl_xor(mx, msk));
        const unsigned qp = mt * 16 + ((lane >> 4) << 2) + r;
        float sum = 0.f;
#pragma unroll
        for (int nt = 0; nt < 8; ++nt) {
          const float e = exp2f((s[mt][nt][r] - mx) * SC);
          sum += e;
          const unsigned mcol = nt * 16 + (lane & 15);
          pb[swz(qp * 256u + mcol * 2u, qp) >> 1] = f2bf(e);
        }
#pragma unroll
        for (int msk = 1; msk < 16; msk <<= 1) sum += __shfl_xor(sum, msk);
        rinv[mt][r] = 1.0f / sum;
      }
    }

    f32x4 o[2][2];
#pragma unroll
    for (int mt = 0; mt < 2; ++mt)
#pragma unroll
      for (int nt = 0; nt < 2; ++nt) o[mt][nt] = vzero;
#pragma unroll
    for (int kk = 0; kk < 4; ++kk) {
      const unsigned kb = kk * 64u + ((lane >> 4) << 4);
      bf16x8 pa[2], vf[2];
#pragma unroll
      for (int mt = 0; mt < 2; ++mt) {
        const unsigned rq = mt * 16 + (lane & 15);
        pa[mt] = *(const bf16x8*)(pb + (swz(rq * 256u + kb, rq) >> 1));
      }
#pragma unroll
      for (int nt = 0; nt < 2; ++nt) {
        const unsigned dh = nt * 16 + (lane & 15);
        vf[nt] = *(const bf16x8*)(vbb + (swz(dh * 256u + kb, dh) >> 1));
      }
#pragma unroll
      for (int mt = 0; mt < 2; ++mt)
#pragma unroll
        for (int nt = 0; nt < 2; ++nt) o[mt][nt] = mfma16(pa[mt], vf[nt], o[mt][nt]);
    }
#pragma unroll
    for (int mt = 0; mt < 2; ++mt)
#pragma unroll
      for (int nt = 0; nt < 2; ++nt)
#pragma unroll
        for (int r = 0; r < 4; ++r) {
          const long node = cb + p * 32 + mt * 16 + ((lane >> 4) << 2) + r;
          const int col = hd * 32 + nt * 16 + (lane & 15);
          obuf[node * 128 + col] = f2bf(o[mt][nt][r] * rinv[mt][r]);
        }
  }
}

// ---------------------------------------------------------------- graph mean
__global__ void k_gmean(const float* __restrict__ ne, float* __restrict__ ge) {
  const int bs = blockIdx.x, o = threadIdx.x;
  const float* p = ne + (long)bs * 65536 + o;
  float s = 0.f;
#pragma unroll 8
  for (int i = 0; i < 1024; ++i) s += p[(long)i * 64];
  ge[bs * 64 + o] = s * (1.0f / 1024.0f);
}

// ----------------------------------------------------------------
extern "C" void kernel_launch(void* const* d_in, const int* in_sizes, int n_in,
                              void* d_out, int out_size, void* d_ws, size_t ws_size,
                              hipStream_t stream) {
  const float* x = (const float*)d_in[0];
  const float* adj = (const float*)d_in[1];
  const float* mask = (const float*)d_in[2];
  const float* fi = (const float*)d_in[3];
  const float* Win = (const float*)d_in[4];
  const float* bin = (const float*)d_in[5];
  const float* lng = (const float*)d_in[6];
  const float* lnb = (const float*)d_in[7];
  const float* gW = (const float*)d_in[8];
  const float* gB = (const float*)d_in[9];
  const float* bng = (const float*)d_in[10];
  const float* bnb = (const float*)d_in[11];
  const float* Wqkv = (const float*)d_in[12];
  const float* bqkv = (const float*)d_in[13];
  const float* Wo = (const float*)d_in[14];
  const float* bo = (const float*)d_in[15];
  const float* Wout = (const float*)d_in[16];
  const float* bout = (const float*)d_in[17];

  char* ws = (char*)d_ws;
  float* dinv = (float*)ws;            ws += 65536 * 4;
  int* cnt = (int*)ws;                 ws += 65536 * 4;
  float* hv = (float*)ws;              ws += 64 * 128 * 4;
  unsigned short* cols = (unsigned short*)ws;  ws += (size_t)65536 * 128 * 2;
  float* hbuf = (float*)ws;            ws += (size_t)65536 * 128 * 4;
  unsigned short* hwp = (unsigned short*)ws;   ws += (size_t)65536 * 128 * 2;  // also obuf
  unsigned short* hc = (unsigned short*)ws;    ws += (size_t)65536 * 128 * 2;
  unsigned short* qkvb = (unsigned short*)ws;  ws += (size_t)65536 * 384 * 2;

  float* ne = (float*)d_out;
  float* ge = ne + (size_t)4194304;

  k_prep_vec<<<64, 128, 0, stream>>>(x, fi, Win, bin, lng, lnb, hv);
  k_adj<<<16384, 256, 0, stream>>>(adj, cols, cnt, dinv);
  k_bcast<<<4096, 256, 0, stream>>>(hv, hbuf);

  for (int l = 0; l < 3; ++l) {
    k_gemm<128, 0, false, true, false><<<512, 256, 0, stream>>>(
        hbuf, gW + (size_t)l * 128 * 128, nullptr, dinv, nullptr, nullptr, nullptr, hwp);
    k_spmm<<<16384, 256, 0, stream>>>((const unsigned*)hwp, cols, cnt, dinv,
                                      gB + l * 128, bng + l * 128, bnb + l * 128, (unsigned*)hc);
    k_gemm<128, 1, true, false, false><<<dim3(512, 3), 256, 0, stream>>>(
        hc, Wqkv, bqkv, nullptr, nullptr, nullptr, nullptr, qkvb);
    k_attn<<<512, 256, 0, stream>>>(qkvb, hwp);
    k_gemm<128, 2, true, false, false><<<512, 256, 0, stream>>>(
        hwp, Wo, bo, nullptr, nullptr, nullptr, hbuf, nullptr);
  }

  k_gemm<64, 3, false, true, true><<<512, 256, 0, stream>>>(
      hbuf, Wout, bout, nullptr, hv, mask, nullptr, ne);
  k_gmean<<<64, 64, 0, stream>>>(ne, ge);
}

// Round 2
// 462.867 us; speedup vs baseline: 1.2209x; 1.2209x over previous
//
#include <hip/hip_runtime.h>

typedef __bf16 bf16_t;
typedef bf16_t bf16x8 __attribute__((ext_vector_type(8)));
typedef float f32x4 __attribute__((ext_vector_type(4)));

#define DEV static __device__ __forceinline__

constexpr float kBnScale = 0.999995000037499375f;  // 1/sqrt(1+1e-5)

DEV unsigned short f2bf(float f) {
  unsigned u = __builtin_bit_cast(unsigned, f);
  u += 0x7fffu + ((u >> 16) & 1u);
  return (unsigned short)(u >> 16);
}
DEV float bf2f(unsigned short s) {
  return __builtin_bit_cast(float, ((unsigned)s) << 16);
}
DEV f32x4 mfma16(bf16x8 a, bf16x8 b, f32x4 c) {
  return __builtin_amdgcn_mfma_f32_16x16x32_bf16(a, b, c, 0, 0, 0);
}
DEV unsigned swz(unsigned byteoff, unsigned row) { return byteoff ^ ((row & 7u) << 4); }

// ---------------------------------------------------------------- prep: xv = (x*fi)@W_in + b_in ; LayerNorm -> hv [64][128]
__global__ void k_prep_vec(const float* __restrict__ x, const float* __restrict__ fi,
                           const float* __restrict__ Win, const float* __restrict__ bin,
                           const float* __restrict__ lng, const float* __restrict__ lnb,
                           float* __restrict__ hv) {
  const int bs = blockIdx.x, t = threadIdx.x;  // 128 threads
  float acc = bin[t];
  for (int f = 0; f < 64; ++f) acc += x[bs * 64 + f] * fi[f] * Win[f * 128 + t];
  __shared__ float sred[2];
  float ssum = acc;
  for (int m = 1; m < 64; m <<= 1) ssum += __shfl_xor(ssum, m);
  if ((t & 63) == 0) sred[t >> 6] = ssum;
  __syncthreads();
  const float mu = (sred[0] + sred[1]) * (1.0f / 128.0f);
  const float d = acc - mu;
  float vsum = d * d;
  for (int m = 1; m < 64; m <<= 1) vsum += __shfl_xor(vsum, m);
  __syncthreads();
  if ((t & 63) == 0) sred[t >> 6] = vsum;
  __syncthreads();
  const float var = (sred[0] + sred[1]) * (1.0f / 128.0f);
  hv[bs * 128 + t] = d / sqrtf(var + 1e-5f) * lng[t] + lnb[t];
}

// ---------------------------------------------------------------- weights -> bf16, n-major [n][k]
__global__ __launch_bounds__(256) void k_wconv(const float* __restrict__ Wqkv, const float* __restrict__ Wo,
                                               const float* __restrict__ gW, const float* __restrict__ Wout,
                                               unsigned short* __restrict__ WqkvB, unsigned short* __restrict__ WoB,
                                               unsigned short* __restrict__ gWB, unsigned short* __restrict__ WoutB) {
  const int i = blockIdx.x * 256 + threadIdx.x;
  if (i < 49152) {
    WqkvB[i] = f2bf(Wqkv[i]);  // already [384][128] n-major
  } else if (i < 65536) {
    const int j = i - 49152;
    WoB[j] = f2bf(Wo[j]);      // already [128][128] n-major
  } else if (i < 114688) {
    const int j = i - 65536, l = j >> 14, r = j & 16383, n = r >> 7, k = r & 127;
    gWB[j] = f2bf(gW[(l << 14) + k * 128 + n]);  // transpose [k][n] -> [n][k]
  } else {
    const int j = i - 114688, n = j >> 7, k = j & 127;
    WoutB[j] = f2bf(Wout[k * 64 + n]);           // transpose [128][64] -> [64][128]
  }
}

// ---------------------------------------------------------------- adjacency -> ELL (u16 cols, cap 128) + dinv
__global__ __launch_bounds__(256) void k_adj(const float* __restrict__ adj,
                                             unsigned short* __restrict__ cols,
                                             int* __restrict__ cnt, float* __restrict__ dinv) {
  const int w = threadIdx.x >> 6, lane = threadIdx.x & 63;
  const long row = (long)blockIdx.x * 4 + w;
  const float* ap = adj + row * 1024;
  unsigned short* cp = cols + row * 128;
  int c = 0;
  for (int it = 0; it < 16; ++it) {
    const float v = ap[it * 64 + lane];
    const unsigned long long m = __ballot(v != 0.0f);
    const int pos = c + __popcll(m & ((1ull << lane) - 1ull));
    if (v != 0.0f && pos < 128) cp[pos] = (unsigned short)(it * 64 + lane);
    c += __popcll(m);
  }
  if (lane == 0) {
    cnt[row] = c;
    dinv[row] = 1.0f / sqrtf((float)(c + 1));
  }
}

// ---------------------------------------------------------------- S_i = dinv_i*(dinv_i + sum_nbr dinv_j)
__global__ __launch_bounds__(256) void k_scal(const unsigned short* __restrict__ cols,
                                              const int* __restrict__ cnt, const float* __restrict__ dinv,
                                              float* __restrict__ S) {
  const int w = threadIdx.x >> 6, lane = threadIdx.x & 63;
  const long row = (long)blockIdx.x * 4 + w;
  const int cn = cnt[row] < 128 ? cnt[row] : 128;
  const long bsbase = row & ~1023L;
  const int c0 = cols[row * 128 + lane];
  const int c1 = cols[row * 128 + 64 + lane];
  float s = 0.f;
  if (lane < cn) s += dinv[bsbase + c0];
  if (lane + 64 < cn) s += dinv[bsbase + c1];
  for (int m = 1; m < 64; m <<= 1) s += __shfl_xor(s, m);
  if (lane == 0) {
    const float d = dinv[row];
    S[row] = d * (d + s);
  }
}

// ---------------------------------------------------------------- hw0s[bs][c] = (hv[bs] @ gW0)[c] * bnScale * bng0[c]
__global__ void k_hw0(const float* __restrict__ hv, const float* __restrict__ gW0,
                      const float* __restrict__ bng0, float* __restrict__ hw0s) {
  const int bs = blockIdx.x, c = threadIdx.x;  // 128 threads
  float acc = 0.f;
  for (int k = 0; k < 128; ++k) acc += hv[bs * 128 + k] * gW0[k * 128 + c];
  hw0s[bs * 128 + c] = acc * kBnScale * bng0[c];
}

// ---------------------------------------------------------------- QKV GEMM: [128-row tile] @ WqkvB panel -> qkvb bf16
// L0: A_row[k] = S_i * hw0s[bs][k] + (gb0[k]*bnScale*bng0[k] + bnb0[k]); else A = hc (bf16)
template <bool L0>
__global__ __launch_bounds__(256) void k_qkv(const unsigned short* __restrict__ hc,
                                             const unsigned short* __restrict__ WqkvB,
                                             const float* __restrict__ bqkv,
                                             const float* __restrict__ S, const float* __restrict__ hw0s,
                                             const float* __restrict__ gb0, const float* __restrict__ bng0,
                                             const float* __restrict__ bnb0,
                                             unsigned short* __restrict__ qkvb) {
  __shared__ __align__(16) unsigned short Ab[128 * 128];
  __shared__ __align__(16) unsigned short Bb[128 * 128];
  const int t = threadIdx.x;
  const long blockRow = (long)blockIdx.x * 128;
  const int pan = blockIdx.y;
  const int bs = (int)(blockRow >> 10);

  if constexpr (L0) {
#pragma unroll
    for (int i = 0; i < 16; ++i) {
      const int f = (t + i * 256) * 4;
      const unsigned row = f >> 7, k = f & 127;
      const float Sr = S[blockRow + row];
      const float4 hw = *(const float4*)(hw0s + bs * 128 + k);
      const float4 g = *(const float4*)(gb0 + k);
      const float4 bg = *(const float4*)(bng0 + k);
      const float4 bb = *(const float4*)(bnb0 + k);
      float4 v;
      v.x = Sr * hw.x + (g.x * kBnScale * bg.x + bb.x);
      v.y = Sr * hw.y + (g.y * kBnScale * bg.y + bb.y);
      v.z = Sr * hw.z + (g.z * kBnScale * bg.z + bb.z);
      v.w = Sr * hw.w + (g.w * kBnScale * bg.w + bb.w);
      uint2 u;
      u.x = f2bf(v.x) | ((unsigned)f2bf(v.y) << 16);
      u.y = f2bf(v.z) | ((unsigned)f2bf(v.w) << 16);
      *(uint2*)(Ab + (swz(row * 256u + k * 2u, row) >> 1)) = u;
    }
  } else {
#pragma unroll
    for (int i = 0; i < 8; ++i) {
      const int f = (t + i * 256) * 8;
      const unsigned row = f >> 7, k = f & 127;
      *(uint4*)(Ab + (swz(row * 256u + k * 2u, row) >> 1)) = *(const uint4*)(hc + blockRow * 128 + f);
    }
  }
#pragma unroll
  for (int i = 0; i < 8; ++i) {
    const int f = (t + i * 256) * 8;
    const unsigned n = f >> 7, k = f & 127;
    *(uint4*)(Bb + (swz(n * 256u + k * 2u, n) >> 1)) = *(const uint4*)(WqkvB + pan * 16384 + f);
  }
  __syncthreads();

  const int lane = t & 63, w = t >> 6, wr = w >> 1, wc = w & 1;
  const f32x4 vzero = {0.f, 0.f, 0.f, 0.f};
  f32x4 acc[4][4];
#pragma unroll
  for (int a = 0; a < 4; ++a)
#pragma unroll
    for (int b = 0; b < 4; ++b) acc[a][b] = vzero;
#pragma unroll
  for (int kk = 0; kk < 4; ++kk) {
    const unsigned kb = kk * 64u + ((lane >> 4) << 4);
    bf16x8 af[4], bfr[4];
#pragma unroll
    for (int mt = 0; mt < 4; ++mt) {
      const unsigned row = wr * 64 + mt * 16 + (lane & 15);
      af[mt] = *(const bf16x8*)(Ab + (swz(row * 256u + kb, row) >> 1));
    }
#pragma unroll
    for (int nt = 0; nt < 4; ++nt) {
      const unsigned col = wc * 64 + nt * 16 + (lane & 15);
      bfr[nt] = *(const bf16x8*)(Bb + (swz(col * 256u + kb, col) >> 1));
    }
#pragma unroll
    for (int mt = 0; mt < 4; ++mt)
#pragma unroll
      for (int nt = 0; nt < 4; ++nt) acc[mt][nt] = mfma16(af[mt], bfr[nt], acc[mt][nt]);
  }
#pragma unroll
  for (int mt = 0; mt < 4; ++mt)
#pragma unroll
    for (int nt = 0; nt < 4; ++nt)
#pragma unroll
      for (int r = 0; r < 4; ++r) {
        const long gRow = blockRow + wr * 64 + mt * 16 + ((lane >> 4) << 2) + r;
        const int gCol = wc * 64 + nt * 16 + (lane & 15);
        qkvb[gRow * 384 + pan * 128 + gCol] = f2bf(acc[mt][nt][r] + bqkv[pan * 128 + gCol]);
      }
}

// ---------------------------------------------------------------- SpMM: hc = BN(dinv_i*(sum_nbr hw' + hw'_self) + gcn_b) -> bf16
__global__ __launch_bounds__(256) void k_spmm(const unsigned* __restrict__ hwp,
                                              const unsigned short* __restrict__ cols,
                                              const int* __restrict__ cnt, const float* __restrict__ dinv,
                                              const float* __restrict__ gb, const float* __restrict__ bng,
                                              const float* __restrict__ bnb, unsigned* __restrict__ hc) {
  int b = blockIdx.x;
  b = (b & 7) * 2048 + (b >> 3);  // XCD-chunked swizzle: each XCD works on 8 contiguous graphs (L2-resident)
  const int w = threadIdx.x >> 6, lane = threadIdx.x & 63;
  const long row = (long)b * 4 + w;
  __shared__ unsigned short scol[4][128];
  scol[w][lane] = cols[row * 128 + lane];
  scol[w][lane + 64] = cols[row * 128 + 64 + lane];
  const int cn = cnt[row] < 128 ? cnt[row] : 128;
  const long bsbase = row & ~1023L;
  const unsigned us = hwp[row * 64 + lane];
  float a0 = bf2f((unsigned short)us), a1 = bf2f((unsigned short)(us >> 16));
  int i = 0;
  for (; i + 4 <= cn; i += 4) {
    const int j0 = scol[w][i], j1 = scol[w][i + 1], j2 = scol[w][i + 2], j3 = scol[w][i + 3];
    const unsigned u0 = hwp[(bsbase + j0) * 64 + lane];
    const unsigned u1 = hwp[(bsbase + j1) * 64 + lane];
    const unsigned u2 = hwp[(bsbase + j2) * 64 + lane];
    const unsigned u3 = hwp[(bsbase + j3) * 64 + lane];
    a0 += bf2f((unsigned short)u0) + bf2f((unsigned short)u1) + bf2f((unsigned short)u2) + bf2f((unsigned short)u3);
    a1 += bf2f((unsigned short)(u0 >> 16)) + bf2f((unsigned short)(u1 >> 16)) +
          bf2f((unsigned short)(u2 >> 16)) + bf2f((unsigned short)(u3 >> 16));
  }
  for (; i < cn; ++i) {
    const unsigned uu = hwp[(bsbase + scol[w][i]) * 64 + lane];
    a0 += bf2f((unsigned short)uu);
    a1 += bf2f((unsigned short)(uu >> 16));
  }
  const float di = dinv[row];
  const int c0 = lane * 2, c1 = c0 + 1;
  const float o0 = (di * a0 + gb[c0]) * (kBnScale * bng[c0]) + bnb[c0];
  const float o1 = (di * a1 + gb[c1]) * (kBnScale * bng[c1]) + bnb[c1];
  hc[row * 64 + lane] = (unsigned)f2bf(o0) | ((unsigned)f2bf(o1) << 16);
}

// ---------------------------------------------------------------- chunked MHA: block = one 128-node chunk, wave = one head
__global__ __launch_bounds__(256) void k_attn(const unsigned short* __restrict__ qkv,
                                              unsigned short* __restrict__ obuf) {
  __shared__ __align__(16) unsigned short vT[4 * 32 * 128];  // [head][dh][m], swizzled
  __shared__ __align__(16) unsigned short pl[4 * 32 * 128];  // [head][q][m], swizzled
  const int t = threadIdx.x, lane = t & 63, hd = t >> 6;
  const long cb = (long)blockIdx.x * 128;

  {  // stage v transposed (all threads, all heads)
    const int m = t >> 1, half = t & 1;
    const unsigned short* vrow = qkv + (cb + m) * 384 + 256 + half * 64;
#pragma unroll
    for (int c8 = 0; c8 < 8; ++c8) {
      const uint4 u = *(const uint4*)(vrow + c8 * 8);
      const int col0 = half * 64 + c8 * 8;
      unsigned short* vb = vT + (col0 >> 5) * 4096;
      const int dh0 = col0 & 31;
      const unsigned short e[8] = {(unsigned short)u.x, (unsigned short)(u.x >> 16),
                                   (unsigned short)u.y, (unsigned short)(u.y >> 16),
                                   (unsigned short)u.z, (unsigned short)(u.z >> 16),
                                   (unsigned short)u.w, (unsigned short)(u.w >> 16)};
#pragma unroll
      for (int j = 0; j < 8; ++j) {
        const unsigned dh = dh0 + j;
        vb[swz(dh * 256u + (unsigned)m * 2u, dh) >> 1] = e[j];
      }
    }
  }
  bf16x8 kf[8];
#pragma unroll
  for (int nt = 0; nt < 8; ++nt)
    kf[nt] = *(const bf16x8*)(qkv + (cb + nt * 16 + (lane & 15)) * 384 + 128 + hd * 32 + ((lane >> 4) << 3));
  __syncthreads();

  const unsigned short* vbb = vT + hd * 4096;
  unsigned short* pb = pl + hd * 4096;
  const float SC = 0.17677669529663687f * 1.4426950408889634f;  // dh^-0.5 * log2(e)
  const f32x4 vzero = {0.f, 0.f, 0.f, 0.f};

#pragma unroll 1
  for (int p = 0; p < 4; ++p) {
    bf16x8 qf[2];
#pragma unroll
    for (int mt = 0; mt < 2; ++mt)
      qf[mt] = *(const bf16x8*)(qkv + (cb + p * 32 + mt * 16 + (lane & 15)) * 384 + hd * 32 + ((lane >> 4) << 3));
    f32x4 s[2][8];
#pragma unroll
    for (int mt = 0; mt < 2; ++mt)
#pragma unroll
      for (int nt = 0; nt < 8; ++nt) s[mt][nt] = vzero;
#pragma unroll
    for (int nt = 0; nt < 8; ++nt)
#pragma unroll
      for (int mt = 0; mt < 2; ++mt) s[mt][nt] = mfma16(qf[mt], kf[nt], s[mt][nt]);

    float rinv[2][4];
#pragma unroll
    for (int mt = 0; mt < 2; ++mt) {
#pragma unroll
      for (int r = 0; r < 4; ++r) {
        float mx = s[mt][0][r];
#pragma unroll
        for (int nt = 1; nt < 8; ++nt) mx = fmaxf(mx, s[mt][nt][r]);
#pragma unroll
        for (int msk = 1; msk < 16; msk <<= 1) mx = fmaxf(mx, __shfl_xor(mx, msk));
        const unsigned qp = mt * 16 + ((lane >> 4) << 2) + r;
        float sum = 0.f;
#pragma unroll
        for (int nt = 0; nt < 8; ++nt) {
          const float e = exp2f((s[mt][nt][r] - mx) * SC);
          sum += e;
          const unsigned mcol = nt * 16 + (lane & 15);
          pb[swz(qp * 256u + mcol * 2u, qp) >> 1] = f2bf(e);
        }
#pragma unroll
        for (int msk = 1; msk < 16; msk <<= 1) sum += __shfl_xor(sum, msk);
        rinv[mt][r] = 1.0f / sum;
      }
    }

    f32x4 o[2][2];
#pragma unroll
    for (int mt = 0; mt < 2; ++mt)
#pragma unroll
      for (int nt = 0; nt < 2; ++nt) o[mt][nt] = vzero;
#pragma unroll
    for (int kk = 0; kk < 4; ++kk) {
      const unsigned kb = kk * 64u + ((lane >> 4) << 4);
      bf16x8 pa[2], vf[2];
#pragma unroll
      for (int mt = 0; mt < 2; ++mt) {
        const unsigned rq = mt * 16 + (lane & 15);
        pa[mt] = *(const bf16x8*)(pb + (swz(rq * 256u + kb, rq) >> 1));
      }
#pragma unroll
      for (int nt = 0; nt < 2; ++nt) {
        const unsigned dh = nt * 16 + (lane & 15);
        vf[nt] = *(const bf16x8*)(vbb + (swz(dh * 256u + kb, dh) >> 1));
      }
#pragma unroll
      for (int mt = 0; mt < 2; ++mt)
#pragma unroll
        for (int nt = 0; nt < 2; ++nt) o[mt][nt] = mfma16(pa[mt], vf[nt], o[mt][nt]);
    }
#pragma unroll
    for (int mt = 0; mt < 2; ++mt)
#pragma unroll
      for (int nt = 0; nt < 2; ++nt)
#pragma unroll
        for (int r = 0; r < 4; ++r) {
          const long node = cb + p * 32 + mt * 16 + ((lane >> 4) << 2) + r;
          const int col = hd * 32 + nt * 16 + (lane & 15);
          obuf[node * 128 + col] = f2bf(o[mt][nt][r] * rinv[mt][r]);
        }
  }
}

// ---------------------------------------------------------------- fused: T = h_prev + relu(aout@Wo^T + bo) [+hv if MODE2]
// MODE 0: h_prev = hv bcast, write hbuf, chain @gW[1] * dinv -> hwp
// MODE 1: h_prev = hbuf,     write hbuf, chain @gW[2] * dinv -> hwp
// MODE 2: h_prev = hbuf + hv (h_init),   chain @Wout + bout, *mask -> ne
template <int MODE>
__global__ __launch_bounds__(256) void k_fuse2(const unsigned short* __restrict__ aout,
                                               const unsigned short* __restrict__ WoB,
                                               const unsigned short* __restrict__ B2,
                                               const float* __restrict__ bo, const float* __restrict__ hv,
                                               const float* __restrict__ dinv, const float* __restrict__ bout,
                                               const float* __restrict__ mask, float* __restrict__ hbuf,
                                               unsigned short* __restrict__ hwp, float* __restrict__ ne) {
  __shared__ __align__(16) unsigned short Ab[128 * 128];
  __shared__ __align__(16) unsigned short Bb[128 * 128];
  const int t = threadIdx.x;
  const long blockRow = (long)blockIdx.x * 128;
  const int bs = (int)(blockRow >> 10);
  const int lane = t & 63, w = t >> 6, wr = w >> 1, wc = w & 1;

#pragma unroll
  for (int i = 0; i < 8; ++i) {
    const int f = (t + i * 256) * 8;
    const unsigned row = f >> 7, k = f & 127;
    *(uint4*)(Ab + (swz(row * 256u + k * 2u, row) >> 1)) = *(const uint4*)(aout + blockRow * 128 + f);
    *(uint4*)(Bb + (swz(row * 256u + k * 2u, row) >> 1)) = *(const uint4*)(WoB + f);
  }
  __syncthreads();

  const f32x4 vzero = {0.f, 0.f, 0.f, 0.f};
  f32x4 acc[4][4];
#pragma unroll
  for (int a = 0; a < 4; ++a)
#pragma unroll
    for (int b = 0; b < 4; ++b) acc[a][b] = vzero;
#pragma unroll
  for (int kk = 0; kk < 4; ++kk) {
    const unsigned kb = kk * 64u + ((lane >> 4) << 4);
    bf16x8 af[4], bfr[4];
#pragma unroll
    for (int mt = 0; mt < 4; ++mt) {
      const unsigned row = wr * 64 + mt * 16 + (lane & 15);
      af[mt] = *(const bf16x8*)(Ab + (swz(row * 256u + kb, row) >> 1));
    }
#pragma unroll
    for (int nt = 0; nt < 4; ++nt) {
      const unsigned col = wc * 64 + nt * 16 + (lane & 15);
      bfr[nt] = *(const bf16x8*)(Bb + (swz(col * 256u + kb, col) >> 1));
    }
#pragma unroll
    for (int mt = 0; mt < 4; ++mt)
#pragma unroll
      for (int nt = 0; nt < 4; ++nt) acc[mt][nt] = mfma16(af[mt], bfr[nt], acc[mt][nt]);
  }
  __syncthreads();  // all waves done reading Ab/Bb

  // epilogue1: T -> Ab (bf16, swizzled); h_new -> hbuf (MODE<2)
#pragma unroll
  for (int mt = 0; mt < 4; ++mt)
#pragma unroll
    for (int nt = 0; nt < 4; ++nt)
#pragma unroll
      for (int r = 0; r < 4; ++r) {
        const unsigned lRow = wr * 64 + mt * 16 + ((lane >> 4) << 2) + r;
        const long gRow = blockRow + lRow;
        const int gCol = wc * 64 + nt * 16 + (lane & 15);
        float v = acc[mt][nt][r] + bo[gCol];
        v = v > 0.f ? v : 0.f;
        if constexpr (MODE == 0) {
          v += hv[bs * 128 + gCol];
        } else {
          v += hbuf[gRow * 128 + gCol];
          if constexpr (MODE == 2) v += hv[bs * 128 + gCol];
        }
        if constexpr (MODE < 2) hbuf[gRow * 128 + gCol] = v;
        Ab[swz(lRow * 256u + (unsigned)gCol * 2u, lRow) >> 1] = f2bf(v);
      }

  // stage B2 into Bb
  if constexpr (MODE < 2) {
#pragma unroll
    for (int i = 0; i < 8; ++i) {
      const int f = (t + i * 256) * 8;
      const unsigned n = f >> 7, k = f & 127;
      *(uint4*)(Bb + (swz(n * 256u + k * 2u, n) >> 1)) = *(const uint4*)(B2 + f);
    }
  } else {
#pragma unroll
    for (int i = 0; i < 4; ++i) {
      const int f = (t + i * 256) * 8;
      const unsigned n = f >> 7, k = f & 127;
      *(uint4*)(Bb + (swz(n * 256u + k * 2u, n) >> 1)) = *(const uint4*)(B2 + f);
    }
  }
  __syncthreads();

  constexpr int NT2 = (MODE < 2) ? 4 : 2;
  constexpr int WCOL = (MODE < 2) ? 64 : 32;
  f32x4 acc2[4][NT2];
#pragma unroll
  for (int a = 0; a < 4; ++a)
#pragma unroll
    for (int b = 0; b < NT2; ++b) acc2[a][b] = vzero;
#pragma unroll
  for (int kk = 0; kk < 4; ++kk) {
    const unsigned kb = kk * 64u + ((lane >> 4) << 4);
    bf16x8 af[4], bfr[NT2];
#pragma unroll
    for (int mt = 0; mt < 4; ++mt) {
      const unsigned row = wr * 64 + mt * 16 + (lane & 15);
      af[mt] = *(const bf16x8*)(Ab + (swz(row * 256u + kb, row) >> 1));
    }
#pragma unroll
    for (int nt = 0; nt < NT2; ++nt) {
      const unsigned col = wc * WCOL + nt * 16 + (lane & 15);
      bfr[nt] = *(const bf16x8*)(Bb + (swz(col * 256u + kb, col) >> 1));
    }
#pragma unroll
    for (int mt = 0; mt < 4; ++mt)
#pragma unroll
      for (int nt = 0; nt < NT2; ++nt) acc2[mt][nt] = mfma16(af[mt], bfr[nt], acc2[mt][nt]);
  }

#pragma unroll
  for (int mt = 0; mt < 4; ++mt)
#pragma unroll
    for (int nt = 0; nt < NT2; ++nt)
#pragma unroll
      for (int r = 0; r < 4; ++r) {
        const long gRow = blockRow + wr * 64 + mt * 16 + ((lane >> 4) << 2) + r;
        const int gCol = wc * WCOL + nt * 16 + (lane & 15);
        if constexpr (MODE < 2) {
          hwp[gRow * 128 + gCol] = f2bf(acc2[mt][nt][r] * dinv[gRow]);
        } else {
          ne[gRow * 64 + gCol] = (acc2[mt][nt][r] + bout[gCol]) * mask[bs];
        }
      }
}

// ---------------------------------------------------------------- graph mean
__global__ void k_gmean(const float* __restrict__ ne, float* __restrict__ ge) {
  const int bs = blockIdx.x, o = threadIdx.x;
  const float* p = ne + (long)bs * 65536 + o;
  float s = 0.f;
#pragma unroll 8
  for (int i = 0; i < 1024; ++i) s += p[(long)i * 64];
  ge[bs * 64 + o] = s * (1.0f / 1024.0f);
}

// ----------------------------------------------------------------
extern "C" void kernel_launch(void* const* d_in, const int* in_sizes, int n_in,
                              void* d_out, int out_size, void* d_ws, size_t ws_size,
                              hipStream_t stream) {
  const float* x = (const float*)d_in[0];
  const float* adj = (const float*)d_in[1];
  const float* mask = (const float*)d_in[2];
  const float* fi = (const float*)d_in[3];
  const float* Win = (const float*)d_in[4];
  const float* bin = (const float*)d_in[5];
  const float* lng = (const float*)d_in[6];
  const float* lnb = (const float*)d_in[7];
  const float* gW = (const float*)d_in[8];
  const float* gB = (const float*)d_in[9];
  const float* bng = (const float*)d_in[10];
  const float* bnb = (const float*)d_in[11];
  const float* Wqkv = (const float*)d_in[12];
  const float* bqkv = (const float*)d_in[13];
  const float* Wo = (const float*)d_in[14];
  const float* bo = (const float*)d_in[15];
  const float* Wout = (const float*)d_in[16];
  const float* bout = (const float*)d_in[17];

  char* ws = (char*)d_ws;
  float* dinv = (float*)ws;                    ws += 65536 * 4;
  int* cnt = (int*)ws;                         ws += 65536 * 4;
  float* S = (float*)ws;                       ws += 65536 * 4;
  float* hv = (float*)ws;                      ws += 64 * 128 * 4;
  float* hw0s = (float*)ws;                    ws += 64 * 128 * 4;
  unsigned short* WqkvB = (unsigned short*)ws; ws += 49152 * 2;
  unsigned short* WoB = (unsigned short*)ws;   ws += 16384 * 2;
  unsigned short* gWB = (unsigned short*)ws;   ws += 49152 * 2;
  unsigned short* WoutB = (unsigned short*)ws; ws += 8192 * 2;
  unsigned short* cols = (unsigned short*)ws;  ws += (size_t)65536 * 128 * 2;
  float* hbuf = (float*)ws;                    ws += (size_t)65536 * 128 * 4;
  unsigned short* hwp = (unsigned short*)ws;   ws += (size_t)65536 * 128 * 2;
  unsigned short* hc = (unsigned short*)ws;    ws += (size_t)65536 * 128 * 2;  // also attn out (stream-ordered reuse)
  unsigned short* qkvb = (unsigned short*)ws;  ws += (size_t)65536 * 384 * 2;
  unsigned short* aout = hc;

  float* ne = (float*)d_out;
  float* ge = ne + (size_t)4194304;

  k_prep_vec<<<64, 128, 0, stream>>>(x, fi, Win, bin, lng, lnb, hv);
  k_wconv<<<480, 256, 0, stream>>>(Wqkv, Wo, gW, Wout, WqkvB, WoB, gWB, WoutB);
  k_adj<<<16384, 256, 0, stream>>>(adj, cols, cnt, dinv);
  k_scal<<<16384, 256, 0, stream>>>(cols, cnt, dinv, S);
  k_hw0<<<64, 128, 0, stream>>>(hv, gW, bng, hw0s);

  // ---- layer 0 (rank-1 GCN folded into QKV A-staging)
  k_qkv<true><<<dim3(512, 3), 256, 0, stream>>>(nullptr, WqkvB, bqkv, S, hw0s, gB, bng, bnb, qkvb);
  k_attn<<<512, 256, 0, stream>>>(qkvb, aout);
  k_fuse2<0><<<512, 256, 0, stream>>>(aout, WoB, gWB + 16384, bo, hv, dinv, nullptr, nullptr, hbuf, hwp, nullptr);

  // ---- layer 1
  k_spmm<<<16384, 256, 0, stream>>>((const unsigned*)hwp, cols, cnt, dinv,
                                    gB + 128, bng + 128, bnb + 128, (unsigned*)hc);
  k_qkv<false><<<dim3(512, 3), 256, 0, stream>>>(hc, WqkvB, bqkv, nullptr, nullptr, nullptr, nullptr, nullptr, qkvb);
  k_attn<<<512, 256, 0, stream>>>(qkvb, aout);
  k_fuse2<1><<<512, 256, 0, stream>>>(aout, WoB, gWB + 32768, bo, hv, dinv, nullptr, nullptr, hbuf, hwp, nullptr);

  // ---- layer 2
  k_spmm<<<16384, 256, 0, stream>>>((const unsigned*)hwp, cols, cnt, dinv,
                                    gB + 256, bng + 256, bnb + 256, (unsigned*)hc);
  k_qkv<false><<<dim3(512, 3), 256, 0, stream>>>(hc, WqkvB, bqkv, nullptr, nullptr, nullptr, nullptr, nullptr, qkvb);
  k_attn<<<512, 256, 0, stream>>>(qkvb, aout);
  k_fuse2<2><<<512, 256, 0, stream>>>(aout, WoB, WoutB, bo, hv, dinv, bout, mask, hbuf, nullptr, ne);

  k_gmean<<<64, 64, 0, stream>>>(ne, ge);
}